// Round 2
// baseline (11003.448 us; speedup 1.0000x reference)
//
#include <hip/hip_runtime.h>

// VanillaRNN: BATCH=1024, SEQ=512, HID=512, OUT=10
// h <- tanh(W_hh @ h + W_hx x_t + b_h), 512 steps, then y = W_yh h + b_y.
//
// Round 2: single persistent kernel. 256 WGs x 128 thr (2 waves).
// WG (g,bg): rows [g*64,+64), batch cols [bg*32,+32); wave w = 16-col half.
// W_hh held entirely in VGPRs (4 Mtiles x 16 kk x f16x8 = 256 VGPR/lane).
// h exchanged through global memory in B-fragment-blocked layout
// (coalesced 16B loads / 8B stores), ping-pong buffers, per-wave
// release/acquire flag protocol (flag = #completed steps). Only waves with
// the same (bg, w) communicate; blockIdx = bg + 32*g makes each group
// XCD-local (perf only — protocol is agent-scope correct regardless).
//
// ws: [0,1MB) hA | [1MB,2MB) hB | [2MB,2.5MB) W-frags | [2.5MB,+2KB) flags.

#define BATCH 1024
#define SEQT  512
#define HID   512
#define OUTD  10
#define NG    8
#define NBG   32

typedef _Float16 f16;
typedef _Float16 f16x8 __attribute__((ext_vector_type(8)));
typedef _Float16 f16x4 __attribute__((ext_vector_type(4)));
typedef float    f32x4 __attribute__((ext_vector_type(4)));

// W_hh fp32 [H][H] -> fp16 A-fragment layout:
// entry ((g*4+mt)*16+kk)*64+lane = f16x8 of A[m][k],
// m = g*64+mt*16+(lane&15), k = kk*32+((lane>>4)&3)*8+j.
__global__ void wconv_kernel(const float* __restrict__ Whh, f16* __restrict__ frag) {
    int id = blockIdx.x * blockDim.x + threadIdx.x;   // 0..32767
    int lane = id & 63;
    int kk   = (id >> 6) & 15;
    int mt   = (id >> 10) & 3;
    int g    = id >> 12;
    int m = g * 64 + mt * 16 + (lane & 15);
    int k = kk * 32 + ((lane >> 4) & 3) * 8;
    const float* src = Whh + (size_t)m * HID + k;
    f16x8 v;
#pragma unroll
    for (int j = 0; j < 8; ++j) v[j] = (f16)src[j];
    *(f16x8*)(frag + (size_t)id * 8) = v;
}

__device__ __forceinline__ float fast_tanh(float v) {
    v = fminf(fmaxf(v, -15.f), 15.f);
    float e = __expf(2.f * v);
    return (e - 1.f) * __builtin_amdgcn_rcpf(e + 1.f);
}

__global__ __launch_bounds__(128, 1) void rnn_persistent(
    const f16* __restrict__ frag,   // W_hh A-frags
    f16* __restrict__ hA,           // fragment-blocked h buffers (1 MB each)
    f16* __restrict__ hB,
    int* __restrict__ flags,        // [NBG*2][NG], zeroed
    const float* __restrict__ x,    // [B][T]
    const float* __restrict__ Whx,  // [H]
    const float* __restrict__ bh)   // [H]
{
    const int wg   = blockIdx.x;
    const int bg   = wg & 31;          // batch group (XCD-local across g)
    const int g    = wg >> 5;          // row group
    const int w    = threadIdx.x >> 6; // wave = col half
    const int lane = threadIdx.x & 63;
    const int n    = lane & 15;
    const int q    = lane >> 4;
    const int bg2  = bg * 2 + w;       // 16-col group id

    // ---- W_hh slice into registers (never re-read) ----
    f16x8 Wf[4][16];
    const f16x8* A = (const f16x8*)frag;
#pragma unroll
    for (int mt = 0; mt < 4; ++mt)
#pragma unroll
        for (int kk = 0; kk < 16; ++kk)
            Wf[mt][kk] = A[((g * 4 + mt) * 16 + kk) * 64 + lane];

    // ---- epilogue constants ----
    f32x4 whx4[4], bh4[4];
#pragma unroll
    for (int mt = 0; mt < 4; ++mt) {
        int m0 = g * 64 + mt * 16 + q * 4;
        whx4[mt] = *(const f32x4*)(Whx + m0);
        bh4[mt]  = *(const f32x4*)(bh + m0);
    }

    const int b = bg * 32 + w * 16 + n;     // this lane's batch column
    const float* xp = x + (size_t)b * SEQT;

    int* fl = flags + bg2 * NG;             // my communication group's flags
    const int fidx = lane & 7;

    for (int s = 0; s < SEQT; ++s) {
        const f16* in  = (s & 1) ? hB : hA;
        f16*       out = (s & 1) ? hA : hB; // NOTE: step s writes buf[(s+1)&1]
        // (s even: in=hA out=hB; s odd: in=hB out=hA) — s=511 writes hA.
        float xv = xp[s];

        if (s > 0) {
            int f;
            do {
                f = __hip_atomic_load(fl + fidx, __ATOMIC_RELAXED,
                                      __HIP_MEMORY_SCOPE_AGENT);
            } while (__any(f < s));
            __threadfence();   // acquire: invalidate stale cached h
        }

        // ---- all 16 B-frags in flight (one latency exposure) ----
        f16x8 bf[16];
#pragma unroll
        for (int kk = 0; kk < 16; ++kk)
            bf[kk] = *(const f16x8*)(in + (size_t)((bg2 * 16 + kk) * 64 + lane) * 8);

        f32x4 acc[4] = {{0,0,0,0},{0,0,0,0},{0,0,0,0},{0,0,0,0}};
#pragma unroll
        for (int kk = 0; kk < 16; ++kk)
#pragma unroll
            for (int mt = 0; mt < 4; ++mt)
                acc[mt] = __builtin_amdgcn_mfma_f32_16x16x32_f16(
                    Wf[mt][kk], bf[kk], acc[mt], 0, 0, 0);

        // ---- epilogue: tanh, store in B-frag layout for next step ----
        // C layout: col n = lane&15, row m = g*64 + mt*16 + q*4 + r.
#pragma unroll
        for (int mt = 0; mt < 4; ++mt) {
            f16x4 hv;
#pragma unroll
            for (int r = 0; r < 4; ++r) {
                float pre = acc[mt][r] + whx4[mt][r] * xv + bh4[mt][r];
                hv[r] = (f16)fast_tanh(pre);
            }
            int kkp = g * 2 + (mt >> 1);          // k-block of these rows
            int q2  = (mt & 1) * 2 + (q >> 1);    // consumer quad
            int j0  = (q & 1) * 4;                // consumer j offset
            *(f16x4*)(out + (size_t)(((bg2 * 16 + kkp) * 64 + q2 * 16 + n) * 8 + j0)) = hv;
        }

        __threadfence();   // release: push h to coherence point
        if (lane == 0)
            __hip_atomic_store(fl + g, s + 1, __ATOMIC_RELAXED,
                               __HIP_MEMORY_SCOPE_AGENT);
    }
}

// out[b][o] = by[o] + sum_k Wyh[o][k] * h[b][k], h in fragment-blocked layout.
__global__ __launch_bounds__(256) void y_kernel(
    const f16* __restrict__ h, const float* __restrict__ Wyh,
    const float* __restrict__ by, float* __restrict__ out)
{
    int id = blockIdx.x * blockDim.x + threadIdx.x;
    if (id >= BATCH * OUTD) return;
    int b = id / OUTD, o = id % OUTD;
    int bg2 = b >> 4, n = b & 15;
    const float* wrow = Wyh + (size_t)o * HID;
    float s = by[o];
    for (int kk = 0; kk < 16; ++kk)
#pragma unroll
        for (int q2 = 0; q2 < 4; ++q2) {
            f16x8 hv = *(const f16x8*)(h + (size_t)((bg2 * 16 + kk) * 64 + q2 * 16 + n) * 8);
            const float* wp = wrow + kk * 32 + q2 * 8;
#pragma unroll
            for (int j = 0; j < 8; ++j) s += wp[j] * (float)hv[j];
        }
    out[id] = s;
}

extern "C" void kernel_launch(void* const* d_in, const int* in_sizes, int n_in,
                              void* d_out, int out_size, void* d_ws, size_t ws_size,
                              hipStream_t stream) {
    const float* x   = (const float*)d_in[0];
    const float* Whx = (const float*)d_in[1];
    const float* Whh = (const float*)d_in[2];
    const float* Wyh = (const float*)d_in[3];
    const float* bh  = (const float*)d_in[4];
    const float* by  = (const float*)d_in[5];
    float* out = (float*)d_out;

    char* ws   = (char*)d_ws;
    f16*  hA   = (f16*)ws;                       // 1 MB
    f16*  hB   = (f16*)(ws + (1 << 20));         // 1 MB
    f16*  frag = (f16*)(ws + (2 << 20));         // 512 KB
    int*  flags = (int*)(ws + (2 << 20) + (1 << 19)); // 2 KB

    // h0 = 0; flags = 0 (ws re-poisoned before every call)
    hipMemsetAsync(hA, 0, (size_t)BATCH * HID * sizeof(f16), stream);
    hipMemsetAsync(flags, 0, NBG * 2 * NG * sizeof(int), stream);
    wconv_kernel<<<128, 256, 0, stream>>>(Whh, frag);

    rnn_persistent<<<NG * NBG, 128, 0, stream>>>(frag, hA, hB, flags, x, Whx, bh);

    // step 511 wrote hA
    y_kernel<<<(BATCH * OUTD + 255) / 256, 256, 0, stream>>>(hA, Wyh, by, out);
}

// Round 3
// 1468.094 us; speedup vs baseline: 7.4951x; 7.4951x over previous
//
#include <hip/hip_runtime.h>

// VanillaRNN: BATCH=1024, SEQ=512, HID=512, OUT=10
// h <- tanh(W_hh @ h + W_hx x_t + b_h), 512 steps, then y = W_yh h + b_y.
//
// Round 3: CU-local persistent kernel — NO inter-WG communication.
// 64 WGs x 512 thr (8 waves, 1 WG/CU). Each WG owns 16 batch columns and
// the ENTIRE W_hh: K-cols [0,384) as A-frags in VGPRs (192/lane), K-cols
// [384,512) as A-frags in LDS (128 KB). h (512x16 fp16, B-frag layout,
// 16 KB) lives in LDS, updated in place with 2 barriers/step. Zero fences,
// zero flags, zero cross-XCD traffic in the time loop.
//
// ws: [0,1MB) hG (final h, frag-blocked) | [2MB,2.5MB) W A-frags.

#define BATCH 1024
#define SEQT  512
#define HID   512
#define OUTD  10
#define KR    12   // kk-blocks (of 32) in registers: K=384
#define NKK   16   // total kk-blocks

typedef _Float16 f16;
typedef _Float16 f16x8 __attribute__((ext_vector_type(8)));
typedef _Float16 f16x4 __attribute__((ext_vector_type(4)));
typedef float    f32x4 __attribute__((ext_vector_type(4)));

// W_hh fp32 [H][H] -> fp16 A-fragment layout:
// entry ((g*4+mt)*16+kk)*64+lane = f16x8 of A[m][k],
// m = g*64+mt*16+(lane&15), k = kk*32+((lane>>4)&3)*8+j.
__global__ void wconv_kernel(const float* __restrict__ Whh, f16* __restrict__ frag) {
    int id = blockIdx.x * blockDim.x + threadIdx.x;   // 0..32767
    int lane = id & 63;
    int kk   = (id >> 6) & 15;
    int mt   = (id >> 10) & 3;
    int g    = id >> 12;
    int m = g * 64 + mt * 16 + (lane & 15);
    int k = kk * 32 + ((lane >> 4) & 3) * 8;
    const float* src = Whh + (size_t)m * HID + k;
    f16x8 v;
#pragma unroll
    for (int j = 0; j < 8; ++j) v[j] = (f16)src[j];
    *(f16x8*)(frag + (size_t)id * 8) = v;
}

__device__ __forceinline__ float fast_tanh(float v) {
    v = fminf(fmaxf(v, -15.f), 15.f);
    float e = __expf(2.f * v);
    return (e - 1.f) * __builtin_amdgcn_rcpf(e + 1.f);
}

__global__ __launch_bounds__(512, 2) void rnn_cu(
    const f16* __restrict__ frag,   // W_hh A-frags (all 16 kk-blocks)
    f16* __restrict__ hG,           // final h, frag-blocked [64][16][64][8]
    const float* __restrict__ x,    // [B][T]
    const float* __restrict__ Whx,  // [H]
    const float* __restrict__ bh)   // [H]
{
    // HB first so B-frag ds_read offsets (< 16 KB) fit the 16-bit imm.
    __shared__ f16 HB[8192];                    // h, B-frag layout, 16 KB
    __shared__ f16 WL[65536];                   // W A-frags kk 12..15, 128 KB

    const int tid  = threadIdx.x;
    const int w    = tid >> 6;       // wave = row-group of 64 rows
    const int lane = tid & 63;
    const int n    = lane & 15;      // batch col within group
    const int q    = lane >> 4;
    const int bg   = blockIdx.x;     // batch group: cols [bg*16, +16)

    // ---- h(0) = 0 ----
    {
        f16x8 z;
#pragma unroll
        for (int j = 0; j < 8; ++j) z[j] = (f16)0.f;
        *(f16x8*)&HB[tid * 16]     = z;
        *(f16x8*)&HB[tid * 16 + 8] = z;
    }

    const f16x8* A = (const f16x8*)frag;

    // ---- LDS W portion: wave w copies its own (mt, kk 12..15) frags ----
#pragma unroll
    for (int mt = 0; mt < 4; ++mt)
#pragma unroll
        for (int kkl = 0; kkl < 4; ++kkl) {
            int e = ((w * 4 + mt) * 4 + kkl) * 64 + lane;
            *(f16x8*)&WL[e * 8] = A[((w * 4 + mt) * 16 + (KR + kkl)) * 64 + lane];
        }

    // ---- register W portion: kk 0..11 (192 VGPRs/lane) ----
    f16x8 Wr[4][KR];
#pragma unroll
    for (int mt = 0; mt < 4; ++mt)
#pragma unroll
        for (int kk = 0; kk < KR; ++kk)
            Wr[mt][kk] = A[((w * 4 + mt) * 16 + kk) * 64 + lane];

    __syncthreads();

    const int b = bg * 16 + n;
    const float* xp = x + (size_t)b * SEQT;

#pragma unroll 1
    for (int s = 0; s < SEQT; ++s) {
        float xv = xp[s];

        f32x4 acc[4] = {{0,0,0,0},{0,0,0,0},{0,0,0,0},{0,0,0,0}};
#pragma unroll
        for (int kk = 0; kk < NKK; ++kk) {
            f16x8 bf = *(const f16x8*)&HB[(kk * 64 + lane) * 8];
#pragma unroll
            for (int mt = 0; mt < 4; ++mt) {
                f16x8 a;
                if (kk < KR)
                    a = Wr[mt][kk];
                else
                    a = *(const f16x8*)&WL[(((w * 4 + mt) * 4 + (kk - KR)) * 64 + lane) * 8];
                acc[mt] = __builtin_amdgcn_mfma_f32_16x16x32_f16(a, bf, acc[mt], 0, 0, 0);
            }
        }

        __syncthreads();   // all reads of h(s) done before in-place overwrite

        // ---- epilogue: tanh, write h(s+1) in B-frag layout ----
        // C layout: col n = lane&15, row m = w*64 + mt*16 + q*4 + r.
#pragma unroll
        for (int mt = 0; mt < 4; ++mt) {
            int m0 = w * 64 + mt * 16 + q * 4;
            f32x4 whx4 = *(const f32x4*)(Whx + m0);   // L1-hot, not held in regs
            f32x4 bh4  = *(const f32x4*)(bh + m0);
            f16x4 hv;
#pragma unroll
            for (int r = 0; r < 4; ++r) {
                float pre = acc[mt][r] + whx4[r] * xv + bh4[r];
                hv[r] = (f16)fast_tanh(pre);
            }
            int kkd = w * 2 + (mt >> 1);
            int q2  = (mt & 1) * 2 + (q >> 1);
            int j0  = (q & 1) * 4;
            int off = (kkd * 64 + q2 * 16 + n) * 8 + j0;
            if (s < SEQT - 1) {
                *(f16x4*)&HB[off] = hv;
            } else {
                *(f16x4*)(hG + (size_t)(((bg * 16 + kkd) * 64 + q2 * 16 + n) * 8 + j0)) = hv;
            }
        }

        __syncthreads();   // h(s+1) complete before next step's reads
    }
}

// out[b][o] = by[o] + sum_k Wyh[o][k] * h[b][k], h in frag-blocked layout.
__global__ __launch_bounds__(256) void y_kernel(
    const f16* __restrict__ h, const float* __restrict__ Wyh,
    const float* __restrict__ by, float* __restrict__ out)
{
    int id = blockIdx.x * blockDim.x + threadIdx.x;
    if (id >= BATCH * OUTD) return;
    int b = id / OUTD, o = id % OUTD;
    int bg = b >> 4, n = b & 15;
    const float* wrow = Wyh + (size_t)o * HID;
    float s = by[o];
    for (int kk = 0; kk < 16; ++kk)
#pragma unroll
        for (int q2 = 0; q2 < 4; ++q2) {
            f16x8 hv = *(const f16x8*)(h + (size_t)((bg * 16 + kk) * 64 + q2 * 16 + n) * 8);
            const float* wp = wrow + kk * 32 + q2 * 8;
#pragma unroll
            for (int j = 0; j < 8; ++j) s += wp[j] * (float)hv[j];
        }
    out[id] = s;
}

extern "C" void kernel_launch(void* const* d_in, const int* in_sizes, int n_in,
                              void* d_out, int out_size, void* d_ws, size_t ws_size,
                              hipStream_t stream) {
    const float* x   = (const float*)d_in[0];
    const float* Whx = (const float*)d_in[1];
    const float* Whh = (const float*)d_in[2];
    const float* Wyh = (const float*)d_in[3];
    const float* bh  = (const float*)d_in[4];
    const float* by  = (const float*)d_in[5];
    float* out = (float*)d_out;

    char* ws   = (char*)d_ws;
    f16*  hG   = (f16*)ws;                       // 1 MB
    f16*  frag = (f16*)(ws + (2 << 20));         // 512 KB

    wconv_kernel<<<128, 256, 0, stream>>>(Whh, frag);
    rnn_cu<<<64, 512, 0, stream>>>(frag, hG, x, Whx, bh);
    y_kernel<<<(BATCH * OUTD + 255) / 256, 256, 0, stream>>>(hG, Wyh, by, out);
}

// Round 4
// 1306.959 us; speedup vs baseline: 8.4191x; 1.1233x over previous
//
#include <hip/hip_runtime.h>

// VanillaRNN: BATCH=1024, SEQ=512, HID=512, OUT=10
// h <- tanh(W_hh @ h + W_hx x_t + b_h), 512 steps, then y = W_yh h + b_y.
//
// Round 4: same CU-local design as R3 (64 WGs x 512 thr, 1 WG/CU, zero
// inter-WG comm), but fix the register-residency failure R3's counters
// exposed (VGPR_Count=128 -> W was reloaded every step):
//   * amdgpu_waves_per_eu(2,2): LDS (144KB) already limits to 1 WG/CU =
//     2 waves/SIMD, so pin the allocator to the full 256-reg budget.
//   * branch-free split K-loop: kk 0..11 from Wr[48] (static idx -> SROA),
//     kk 12..15 from LDS WL.
//   * Whx/bh epilogue loads kept IN-loop via asm pointer clobber (hoisting
//     them costs 32 regs and triggers the spill).
//
// ws: [0,1MB) hG (final h, frag-blocked) | [2MB,2.5MB) W A-frags.

#define BATCH 1024
#define SEQT  512
#define HID   512
#define OUTD  10
#define KR    12   // kk-blocks (of K=32) in registers: K=384
#define NKK   16

typedef _Float16 f16;
typedef _Float16 f16x8 __attribute__((ext_vector_type(8)));
typedef _Float16 f16x4 __attribute__((ext_vector_type(4)));
typedef float    f32x4 __attribute__((ext_vector_type(4)));

// W_hh fp32 [H][H] -> fp16 A-fragment layout:
// entry ((g*4+mt)*16+kk)*64+lane = f16x8 of A[m][k],
// m = g*64+mt*16+(lane&15), k = kk*32+((lane>>4)&3)*8+j.
__global__ void wconv_kernel(const float* __restrict__ Whh, f16* __restrict__ frag) {
    int id = blockIdx.x * blockDim.x + threadIdx.x;   // 0..32767
    int lane = id & 63;
    int kk   = (id >> 6) & 15;
    int mt   = (id >> 10) & 3;
    int g    = id >> 12;
    int m = g * 64 + mt * 16 + (lane & 15);
    int k = kk * 32 + ((lane >> 4) & 3) * 8;
    const float* src = Whh + (size_t)m * HID + k;
    f16x8 v;
#pragma unroll
    for (int j = 0; j < 8; ++j) v[j] = (f16)src[j];
    *(f16x8*)(frag + (size_t)id * 8) = v;
}

__device__ __forceinline__ float fast_tanh(float v) {
    v = fminf(fmaxf(v, -15.f), 15.f);
    float e = __expf(2.f * v);
    return (e - 1.f) * __builtin_amdgcn_rcpf(e + 1.f);
}

__global__ __launch_bounds__(512)
__attribute__((amdgpu_waves_per_eu(2, 2)))
void rnn_cu(
    const f16* __restrict__ frag,   // W_hh A-frags (all 16 kk-blocks)
    f16* __restrict__ hG,           // final h, frag-blocked [64][16][64][8]
    const float* __restrict__ x,    // [B][T]
    const float* __restrict__ Whx,  // [H]
    const float* __restrict__ bh)   // [H]
{
    // HB first: its ds offsets (<16 KB) fit the 16-bit imm with lane-only base.
    __shared__ f16 HB[8192];                    // h, B-frag layout, 16 KB
    __shared__ f16 WL[65536];                   // W A-frags kk 12..15, 128 KB

    const int tid  = threadIdx.x;
    const int w    = tid >> 6;       // wave = row-group of 64 rows
    const int lane = tid & 63;
    const int n    = lane & 15;      // batch col within group
    const int q    = lane >> 4;
    const int bg   = blockIdx.x;     // batch group: cols [bg*16, +16)

    // ---- h(0) = 0 ----
    {
        f16x8 z;
#pragma unroll
        for (int j = 0; j < 8; ++j) z[j] = (f16)0.f;
        *(f16x8*)&HB[tid * 16]     = z;
        *(f16x8*)&HB[tid * 16 + 8] = z;
    }

    const f16x8* A = (const f16x8*)frag;

    // ---- LDS W portion: wave w stages its (mt, kk 12..15) frags ----
#pragma unroll
    for (int mt = 0; mt < 4; ++mt)
#pragma unroll
        for (int kkl = 0; kkl < 4; ++kkl) {
            int e = ((w * 4 + mt) * 4 + kkl) * 64 + lane;
            *(f16x8*)&WL[e * 8] = A[((w * 4 + mt) * 16 + (KR + kkl)) * 64 + lane];
        }

    // ---- register W portion: kk 0..11, kk-major, static indices ----
    f16x8 Wr[KR * 4];
#pragma unroll
    for (int kk = 0; kk < KR; ++kk)
#pragma unroll
        for (int mt = 0; mt < 4; ++mt)
            Wr[kk * 4 + mt] = A[((w * 4 + mt) * 16 + kk) * 64 + lane];

    __syncthreads();

    const int b = bg * 16 + n;
    const float* xp = x + (size_t)b * SEQT;

#pragma unroll 1
    for (int s = 0; s < SEQT; ++s) {
        float xv = xp[s];

        f32x4 acc[4] = {{0,0,0,0},{0,0,0,0},{0,0,0,0},{0,0,0,0}};

        // phase 1: W from registers (branch-free)
#pragma unroll
        for (int kk = 0; kk < KR; ++kk) {
            f16x8 bf = *(const f16x8*)&HB[(kk * 64 + lane) * 8];
#pragma unroll
            for (int mt = 0; mt < 4; ++mt)
                acc[mt] = __builtin_amdgcn_mfma_f32_16x16x32_f16(
                    Wr[kk * 4 + mt], bf, acc[mt], 0, 0, 0);
        }
        // phase 2: W from LDS
#pragma unroll
        for (int kkl = 0; kkl < 4; ++kkl) {
            f16x8 bf = *(const f16x8*)&HB[((KR + kkl) * 64 + lane) * 8];
#pragma unroll
            for (int mt = 0; mt < 4; ++mt) {
                f16x8 a = *(const f16x8*)&WL[(((w * 4 + mt) * 4 + kkl) * 64 + lane) * 8];
                acc[mt] = __builtin_amdgcn_mfma_f32_16x16x32_f16(
                    a, bf, acc[mt], 0, 0, 0);
            }
        }

        __syncthreads();   // all reads of h(s) done before in-place overwrite

        // Block loop-invariant hoisting of Whx/bh (would cost 32 VGPRs and
        // push past the 256 budget -> spill, which is exactly R3's failure).
        const float* wbp = Whx;
        const float* bbp = bh;
        asm volatile("" : "+v"(wbp), "+v"(bbp));

        // ---- epilogue: tanh, write h(s+1) in B-frag layout ----
        // C layout: col n = lane&15, row m = w*64 + mt*16 + q*4 + r.
#pragma unroll
        for (int mt = 0; mt < 4; ++mt) {
            int m0 = w * 64 + mt * 16 + q * 4;
            f32x4 whx4 = *(const f32x4*)(wbp + m0);
            f32x4 bh4  = *(const f32x4*)(bbp + m0);
            f16x4 hv;
#pragma unroll
            for (int r = 0; r < 4; ++r) {
                float pre = acc[mt][r] + whx4[r] * xv + bh4[r];
                hv[r] = (f16)fast_tanh(pre);
            }
            int kkd = w * 2 + (mt >> 1);
            int q2  = (mt & 1) * 2 + (q >> 1);
            int j0  = (q & 1) * 4;
            int off = (kkd * 64 + q2 * 16 + n) * 8 + j0;
            if (s < SEQT - 1) {
                *(f16x4*)&HB[off] = hv;
            } else {
                *(f16x4*)(hG + (size_t)(((bg * 16 + kkd) * 64 + q2 * 16 + n) * 8 + j0)) = hv;
            }
        }

        __syncthreads();   // h(s+1) complete before next step's reads
    }
}

// out[b][o] = by[o] + sum_k Wyh[o][k] * h[b][k], h in frag-blocked layout.
__global__ __launch_bounds__(256) void y_kernel(
    const f16* __restrict__ h, const float* __restrict__ Wyh,
    const float* __restrict__ by, float* __restrict__ out)
{
    int id = blockIdx.x * blockDim.x + threadIdx.x;
    if (id >= BATCH * OUTD) return;
    int b = id / OUTD, o = id % OUTD;
    int bg = b >> 4, n = b & 15;
    const float* wrow = Wyh + (size_t)o * HID;
    float s = by[o];
    for (int kk = 0; kk < 16; ++kk)
#pragma unroll
        for (int q2 = 0; q2 < 4; ++q2) {
            f16x8 hv = *(const f16x8*)(h + (size_t)((bg * 16 + kk) * 64 + q2 * 16 + n) * 8);
            const float* wp = wrow + kk * 32 + q2 * 8;
#pragma unroll
            for (int j = 0; j < 8; ++j) s += wp[j] * (float)hv[j];
        }
    out[id] = s;
}

extern "C" void kernel_launch(void* const* d_in, const int* in_sizes, int n_in,
                              void* d_out, int out_size, void* d_ws, size_t ws_size,
                              hipStream_t stream) {
    const float* x   = (const float*)d_in[0];
    const float* Whx = (const float*)d_in[1];
    const float* Whh = (const float*)d_in[2];
    const float* Wyh = (const float*)d_in[3];
    const float* bh  = (const float*)d_in[4];
    const float* by  = (const float*)d_in[5];
    float* out = (float*)d_out;

    char* ws   = (char*)d_ws;
    f16*  hG   = (f16*)ws;                       // 1 MB
    f16*  frag = (f16*)(ws + (2 << 20));         // 512 KB

    wconv_kernel<<<128, 256, 0, stream>>>(Whh, frag);
    rnn_cu<<<64, 512, 0, stream>>>(frag, hG, x, Whx, bh);
    y_kernel<<<(BATCH * OUTD + 255) / 256, 256, 0, stream>>>(hG, Wyh, by, out);
}